// Round 4
// baseline (591.541 us; speedup 1.0000x reference)
//
#include <hip/hip_runtime.h>
#include <hip/hip_fp16.h>
#include <math.h>

#define H 8
#define C 32
#define HC 256      // H*C
#define FE 16
#define FIN 128
#define NEG_SLOPE 0.2f

typedef __attribute__((ext_vector_type(8))) short bf16x8;
typedef __attribute__((ext_vector_type(4))) float f32x4;

__device__ __forceinline__ unsigned short f2bf(float f) {
  unsigned int u = __float_as_uint(f);
  unsigned int lsb = (u >> 16) & 1u;
  u += 0x7fffu + lsb;               // round-to-nearest-even
  return (unsigned short)(u >> 16);
}
__device__ __forceinline__ float bf2f(unsigned short s) {
  return __uint_as_float(((unsigned int)s) << 16);
}
__device__ __forceinline__ unsigned short f2h(float f) {
  return __half_as_ushort(__float2half(f));
}
__device__ __forceinline__ float h2f(unsigned short s) {
  return __half2float(__ushort_as_half(s));
}

// split 8 fp32 into hi (truncated bf16) + lo (RNE bf16 of residual)
__device__ __forceinline__ void split8(const float* v, bf16x8& hi, bf16x8& lo) {
#pragma unroll
  for (int i = 0; i < 8; ++i) {
    unsigned int u = __float_as_uint(v[i]);
    unsigned int hu = u & 0xffff0000u;
    float r = v[i] - __uint_as_float(hu);
    hi[i] = (short)(hu >> 16);
    lo[i] = (short)f2bf(r);
  }
}

// ---------------- xh^T = W @ x^T via MFMA split-bf16 (3 passes, fp32-grade accuracy) ----------------
__global__ __launch_bounds__(256) void k_xh(const float* __restrict__ x,
                                            const unsigned short* __restrict__ Whi,
                                            const unsigned short* __restrict__ Wlo,
                                            const float* __restrict__ att_src,
                                            const float* __restrict__ att_dst,
                                            unsigned short* __restrict__ xhb,
                                            float* __restrict__ a_dst,
                                            unsigned short* __restrict__ a_srch, int N) {
  int t = threadIdx.x;
  int w = t >> 6, lane = t & 63;
  int n15 = lane & 15, q = lane >> 4;
  int nodeBase = blockIdx.x * 128 + w * 32;      // + nt*16 + n15
  int chBase = blockIdx.y * 128;                 // + mt*16 + (row idx)

  f32x4 acc[8][2];
#pragma unroll
  for (int mt = 0; mt < 8; ++mt)
#pragma unroll
    for (int nt = 0; nt < 2; ++nt) acc[mt][nt] = (f32x4)(0.f);

  for (int ks = 0; ks < 4; ++ks) {
    int kOff = ks * 32 + q * 8;
    bf16x8 Bhi[2], Blo[2];
#pragma unroll
    for (int nt = 0; nt < 2; ++nt) {
      int node = nodeBase + nt * 16 + n15;
      int rn = (node < N) ? node : (N - 1);
      const float* px = &x[(size_t)rn * FIN + kOff];
      float vb[8];
      *(float4*)&vb[0] = *(const float4*)px;
      *(float4*)&vb[4] = *(const float4*)(px + 4);
      split8(vb, Bhi[nt], Blo[nt]);
    }
#pragma unroll
    for (int mt = 0; mt < 8; ++mt) {
      int widx = ((chBase + mt * 16 + n15) << 7) + kOff;
      bf16x8 Ahi = *(const bf16x8*)&Whi[widx];
      bf16x8 Alo = *(const bf16x8*)&Wlo[widx];
#pragma unroll
      for (int nt = 0; nt < 2; ++nt) {
        acc[mt][nt] = __builtin_amdgcn_mfma_f32_16x16x32_bf16(Ahi, Bhi[nt], acc[mt][nt], 0, 0, 0);
        acc[mt][nt] = __builtin_amdgcn_mfma_f32_16x16x32_bf16(Ahi, Blo[nt], acc[mt][nt], 0, 0, 0);
        acc[mt][nt] = __builtin_amdgcn_mfma_f32_16x16x32_bf16(Alo, Bhi[nt], acc[mt][nt], 0, 0, 0);
      }
    }
  }

  // Epilogue. C/D layout: col(lane&15)=node, row=q*4+reg = channel within tile.
  float ps[2][4] = {{0.f,0.f,0.f,0.f},{0.f,0.f,0.f,0.f}};
  float pd[2][4] = {{0.f,0.f,0.f,0.f},{0.f,0.f,0.f,0.f}};
#pragma unroll
  for (int mt = 0; mt < 8; ++mt) {
    int hl = mt >> 1;
#pragma unroll
    for (int r = 0; r < 4; ++r) {
      int ch = chBase + mt * 16 + q * 4 + r;
      float as_c = att_src[ch], ad_c = att_dst[ch];
#pragma unroll
      for (int nt = 0; nt < 2; ++nt) {
        float val = acc[mt][nt][r];
        ps[nt][hl] = fmaf(val, as_c, ps[nt][hl]);
        pd[nt][hl] = fmaf(val, ad_c, pd[nt][hl]);
      }
    }
#pragma unroll
    for (int nt = 0; nt < 2; ++nt) {
      int node = nodeBase + nt * 16 + n15;
      if (node < N) {
        ushort4 us;
        us.x = f2bf(acc[mt][nt][0]); us.y = f2bf(acc[mt][nt][1]);
        us.z = f2bf(acc[mt][nt][2]); us.w = f2bf(acc[mt][nt][3]);
        *(ushort4*)&xhb[(size_t)node * HC + chBase + mt * 16 + q * 4] = us;
      }
    }
  }
#pragma unroll
  for (int nt = 0; nt < 2; ++nt)
#pragma unroll
    for (int hl = 0; hl < 4; ++hl) {
      ps[nt][hl] += __shfl_xor(ps[nt][hl], 16, 64);
      ps[nt][hl] += __shfl_xor(ps[nt][hl], 32, 64);
      pd[nt][hl] += __shfl_xor(pd[nt][hl], 16, 64);
      pd[nt][hl] += __shfl_xor(pd[nt][hl], 32, 64);
    }
  if (q == 0) {
#pragma unroll
    for (int nt = 0; nt < 2; ++nt) {
      int node = nodeBase + nt * 16 + n15;
      if (node < N) {
        *(float4*)&a_dst[node * H + blockIdx.y * 4] = make_float4(pd[nt][0], pd[nt][1], pd[nt][2], pd[nt][3]);
        unsigned int p0 = (unsigned int)f2h(ps[nt][0]) | ((unsigned int)f2h(ps[nt][1]) << 16);
        unsigned int p1 = (unsigned int)f2h(ps[nt][2]) | ((unsigned int)f2h(ps[nt][3]) << 16);
        *(uint2*)&a_srch[(size_t)node * H + blockIdx.y * 4] = make_uint2(p0, p1);
      }
    }
  }
}

// ---------------- degree histogram + rank; also splits W into bf16 hi/lo (fused one-off) ----------------
__global__ __launch_bounds__(256) void k_deg(const int* __restrict__ ei,
                                             int* __restrict__ deg,
                                             int* __restrict__ rank,
                                             const float* __restrict__ W,
                                             unsigned short* __restrict__ Whi,
                                             unsigned short* __restrict__ Wlo, int E) {
  int e = blockIdx.x * 256 + threadIdx.x;
  if (e < HC * FIN) {
    float v = W[e];
    unsigned int u = __float_as_uint(v);
    unsigned int hu = u & 0xffff0000u;
    Whi[e] = (unsigned short)(hu >> 16);
    Wlo[e] = f2bf(v - __uint_as_float(hu));
  }
  if (e < E) rank[e] = atomicAdd(&deg[ei[E + e]], 1);
}

// ---------------- scan stage 1: per-block sums ----------------
__global__ __launch_bounds__(256) void k_scan1(const int* __restrict__ deg,
                                               int* __restrict__ bsum, int N) {
  int t = threadIdx.x;
  int i = blockIdx.x * 256 + t;
  int v = (i < N) ? deg[i] : 0;
#pragma unroll
  for (int m = 1; m < 64; m <<= 1) v += __shfl_xor(v, m, 64);
  __shared__ int wsum[4];
  if ((t & 63) == 0) wsum[t >> 6] = v;
  __syncthreads();
  if (t == 0) bsum[blockIdx.x] = wsum[0] + wsum[1] + wsum[2] + wsum[3];
}

// ---------------- scan stage 2+3 fused: every block scans bsum in LDS, then local scan ----------------
__global__ __launch_bounds__(256) void k_scan23(const int* __restrict__ deg,
                                                const int* __restrict__ bsum,
                                                int* __restrict__ rowptr, int N, int E, int nb) {
  __shared__ int sb[256];
  __shared__ int buf[256];
  int t = threadIdx.x;
  sb[t] = (t < nb) ? bsum[t] : 0;
  int i = blockIdx.x * 256 + t;
  int v = (i < N) ? deg[i] : 0;
  buf[t] = v;
  __syncthreads();
  for (int off = 1; off < 256; off <<= 1) {
    int y1 = (t >= off) ? sb[t - off] : 0;
    int y2 = (t >= off) ? buf[t - off] : 0;
    __syncthreads();
    sb[t] += y1;
    buf[t] += y2;
    __syncthreads();
  }
  int bofs = (blockIdx.x == 0) ? 0 : sb[blockIdx.x - 1];
  if (i < N) rowptr[i] = bofs + buf[t] - v;
  if (i == 0) rowptr[N] = E;
}

// ---------------- per-edge (2 edges/thread): a_edge = ea @ M, fold fp16 a_src[src] ----------------
// record[pos] = 8 x fp16 = fp16(a_edge[h] + a_src[src][h])  (16 B)
// aesum[dst][h] += a_edge[h] via f32 atomics (self-loop mean numerator, edge-order, no chain)
__global__ __launch_bounds__(256) void k_edge_scatter(const int* __restrict__ ei,
                                                      const float* __restrict__ ea,
                                                      const float* __restrict__ W_edge,
                                                      const float* __restrict__ att_edge,
                                                      const unsigned short* __restrict__ a_srch,
                                                      const int* __restrict__ rowptr,
                                                      const int* __restrict__ rank,
                                                      unsigned short* __restrict__ recs16,
                                                      int* __restrict__ sarr,
                                                      float* __restrict__ aesum, int E) {
  __shared__ float Ms[FE * H];
  int t = threadIdx.x;
  if (t < FE * H) {          // M[f][h] = sum_c W_edge[(h*C+c)*FE+f] * att_edge[h*C+c]
    int f = t >> 3, h = t & 7;
    float acc = 0.f;
#pragma unroll
    for (int c = 0; c < C; ++c)
      acc += W_edge[(h * C + c) * FE + f] * att_edge[h * C + c];
    Ms[f * H + h] = acc;
  }
  __syncthreads();
  int e0 = blockIdx.x * 512 + t;
  int e1 = e0 + 256;
  bool va = (e0 < E), vb = (e1 < E);
  int ca = va ? e0 : 0, cb = vb ? e1 : 0;
  // ---- independent loads first (2 chains in flight) ----
  int s0 = ei[ca], d0 = ei[E + ca];
  int s1 = ei[cb], d1 = ei[E + cb];
  const float4* pA = (const float4*)&ea[(size_t)ca * FE];
  const float4* pB = (const float4*)&ea[(size_t)cb * FE];
  float4 A0 = pA[0], A1 = pA[1], A2 = pA[2], A3 = pA[3];
  float4 B0 = pB[0], B1 = pB[1], B2 = pB[2], B3 = pB[3];
  int rk0 = rank[ca], rk1 = rank[cb];
  // ---- one dependent hop, both chains issued together ----
  int rp0 = rowptr[d0], rp1 = rowptr[d1];
  uint4 asA = *(const uint4*)&a_srch[(size_t)s0 * H];
  uint4 asB = *(const uint4*)&a_srch[(size_t)s1 * H];

  float eavA[FE] = {A0.x, A0.y, A0.z, A0.w, A1.x, A1.y, A1.z, A1.w,
                    A2.x, A2.y, A2.z, A2.w, A3.x, A3.y, A3.z, A3.w};
  float eavB[FE] = {B0.x, B0.y, B0.z, B0.w, B1.x, B1.y, B1.z, B1.w,
                    B2.x, B2.y, B2.z, B2.w, B3.x, B3.y, B3.z, B3.w};
  float oA[H], oB[H];
#pragma unroll
  for (int h = 0; h < H; ++h) {
    float aa = 0.f, ab = 0.f;
#pragma unroll
    for (int f = 0; f < FE; ++f) {
      float m = Ms[f * H + h];
      aa += eavA[f] * m;
      ab += eavB[f] * m;
    }
    oA[h] = aa; oB[h] = ab;
  }
  unsigned int asw[2][4] = {{asA.x, asA.y, asA.z, asA.w}, {asB.x, asB.y, asB.z, asB.w}};
  if (va) {
    int pos = rp0 + rk0;
    unsigned int r01 = 0, r23 = 0, r45 = 0, r67 = 0;
    unsigned int rw[4];
#pragma unroll
    for (int p = 0; p < 4; ++p) {
      float as_lo = h2f((unsigned short)(asw[0][p] & 0xffffu));
      float as_hi = h2f((unsigned short)(asw[0][p] >> 16));
      rw[p] = (unsigned int)f2h(oA[2 * p] + as_lo) | ((unsigned int)f2h(oA[2 * p + 1] + as_hi) << 16);
    }
    r01 = rw[0]; r23 = rw[1]; r45 = rw[2]; r67 = rw[3];
    *(uint4*)&recs16[(size_t)pos * 8] = make_uint4(r01, r23, r45, r67);
    sarr[pos] = s0;
#pragma unroll
    for (int h = 0; h < H; ++h) atomicAdd(&aesum[(size_t)d0 * H + h], oA[h]);
  }
  if (vb) {
    int pos = rp1 + rk1;
    unsigned int rw[4];
#pragma unroll
    for (int p = 0; p < 4; ++p) {
      float as_lo = h2f((unsigned short)(asw[1][p] & 0xffffu));
      float as_hi = h2f((unsigned short)(asw[1][p] >> 16));
      rw[p] = (unsigned int)f2h(oB[2 * p] + as_lo) | ((unsigned int)f2h(oB[2 * p + 1] + as_hi) << 16);
    }
    *(uint4*)&recs16[(size_t)pos * 8] = make_uint4(rw[0], rw[1], rw[2], rw[3]);
    sarr[pos] = s1;
#pragma unroll
    for (int h = 0; h < H; ++h) atomicAdd(&aesum[(size_t)d1 * H + h], oB[h]);
  }
}

// ---------------- wave-per-node: max-free single-pass softmax + guard-free gather ----------------
// exp(alpha)/sum(exp(alpha)) == reference's max-shifted softmax; |alpha| <~ 12 so fp32 exp is safe.
__global__ __launch_bounds__(256) void k_node(const unsigned short* __restrict__ xhb,
                                              const unsigned short* __restrict__ a_srch,
                                              const float* __restrict__ a_dst,
                                              const unsigned short* __restrict__ recs16,
                                              const int* __restrict__ sarr,
                                              const int* __restrict__ rowptr,
                                              const float* __restrict__ aesum,
                                              const float* __restrict__ bias,
                                              float* __restrict__ out, int N) {
  __shared__ float wlds[4][512];   // [wave][j*8+h], j<64
  __shared__ int   slds[4][64];
  int wv = threadIdx.x >> 6;
  int lane = threadIdx.x & 63;
  int n = blockIdx.x * 4 + wv;
  if (n >= N) return;
  int start = rowptr[n];
  int deg = rowptr[n + 1] - start;
  int jmax = (deg < 64) ? deg : 64;
  int nit = (jmax + 7) >> 3;           // live 8-edge chunks (wave-uniform -> scalar branch)
  int padded = nit << 3;
  int h = lane & 7, esub = lane >> 3;
  float adst = a_dst[n * H + h];
  float asrc = h2f(a_srch[(size_t)n * H + h]);
  float aes  = aesum[(size_t)n * H + h];

  // src list -> LDS in ONE coalesced load; pad rows point at self (weight 0 in wlds)
  if (lane < padded) slds[wv][lane] = (lane < jmax) ? sarr[start + lane] : n;

  // ---- phase 1a: batch the record loads (2B/lane, fully coalesced per chunk) ----
  const unsigned short* rb = recs16 + (size_t)start * 8 + lane;
  unsigned short u[8];
#pragma unroll
  for (int it = 0; it < 8; ++it) {
    u[it] = 0;
    if (it < nit) {
      int j = it * 8 + esub;
      if (j < jmax) u[it] = rb[it * 64];
    }
  }

  // ---- phase 1b: w = exp(alpha) directly (no max pass) ----
  float den = 0.f;
#pragma unroll
  for (int it = 0; it < 8; ++it)
    if (it < nit) {
      int j = it * 8 + esub;
      float a = h2f(u[it]) + adst;            // (a_edge + a_src) + a_dst
      a = fmaxf(a, NEG_SLOPE * a);            // leaky relu (slope<1)
      float w = (j < jmax) ? __expf(a) : 0.f;
      den += w;
      wlds[wv][it * 64 + lane] = w;           // zero-pad falls out naturally
    }
  for (int j0 = 64; j0 < deg; j0 += 8) {   // overflow deg>64 (rare)
    int j = j0 + esub;
    if (j < deg) {
      float a = h2f(recs16[(size_t)(start + j) * 8 + h]) + adst;
      a = fmaxf(a, NEG_SLOPE * a);
      den += __expf(a);
    }
  }
#pragma unroll
  for (int m = 8; m <= 32; m <<= 1) den += __shfl_xor(den, m, 64);
  float aself = asrc + adst + aes / fmaxf((float)deg, 1.f);
  aself = fmaxf(aself, NEG_SLOPE * aself);
  float wself = __expf(aself);
  float inv = 1.f / (den + wself);

  // ---- phase 2: guard-free unroll-8 gather over zero-padded lists ----
  int hc = lane >> 3;
  float inv_c  = __shfl(inv, hc, 64);
  float ws_c   = __shfl(wself, hc, 64);
  float adst_c = __shfl(adst, hc, 64);
  float accx, accy, accz, accw;
  {
    uint2 su = ((const uint2*)(xhb + (((size_t)n) << 8)))[lane];
    accx = ws_c * __uint_as_float(su.x << 16);
    accy = ws_c * __uint_as_float(su.x & 0xffff0000u);
    accz = ws_c * __uint_as_float(su.y << 16);
    accw = ws_c * __uint_as_float(su.y & 0xffff0000u);
  }
  for (int j0 = 0; j0 < padded; j0 += 8) {
    uint2 v[8]; float wj[8];
#pragma unroll
    for (int k = 0; k < 8; ++k) {
      wj[k] = wlds[wv][(j0 + k) * 8 + hc];
      v[k] = ((const uint2*)(xhb + (((size_t)slds[wv][j0 + k]) << 8)))[lane];
    }
#pragma unroll
    for (int k = 0; k < 8; ++k) {
      accx = fmaf(__uint_as_float(v[k].x << 16), wj[k], accx);
      accy = fmaf(__uint_as_float(v[k].x & 0xffff0000u), wj[k], accy);
      accz = fmaf(__uint_as_float(v[k].y << 16), wj[k], accz);
      accw = fmaf(__uint_as_float(v[k].y & 0xffff0000u), wj[k], accw);
    }
  }
  for (int j = 64; j < deg; ++j) {       // overflow: recompute weight from record
    int src = sarr[start + j];
    float a = h2f(recs16[(size_t)(start + j) * 8 + hc]) + adst_c;
    a = fmaxf(a, NEG_SLOPE * a);
    float wj = __expf(a);
    uint2 v = ((const uint2*)(xhb + (((size_t)src) << 8)))[lane];
    accx = fmaf(__uint_as_float(v.x << 16), wj, accx);
    accy = fmaf(__uint_as_float(v.x & 0xffff0000u), wj, accy);
    accz = fmaf(__uint_as_float(v.y << 16), wj, accz);
    accw = fmaf(__uint_as_float(v.y & 0xffff0000u), wj, accw);
  }
  accx *= inv_c; accy *= inv_c; accz *= inv_c; accw *= inv_c;

  // head mean across hc (xor 8,16,32)
#pragma unroll
  for (int m = 8; m <= 32; m <<= 1) {
    accx += __shfl_xor(accx, m, 64);
    accy += __shfl_xor(accy, m, 64);
    accz += __shfl_xor(accz, m, 64);
    accw += __shfl_xor(accw, m, 64);
  }
  if (lane < 8) {
    float4 b = ((const float4*)bias)[lane];
    float4 o;
    o.x = accx * 0.125f + b.x;
    o.y = accy * 0.125f + b.y;
    o.z = accz * 0.125f + b.z;
    o.w = accw * 0.125f + b.w;
    ((float4*)&out[(size_t)n * C])[lane] = o;
  }
}

extern "C" void kernel_launch(void* const* d_in, const int* in_sizes, int n_in,
                              void* d_out, int out_size, void* d_ws, size_t ws_size,
                              hipStream_t stream) {
  const float* x        = (const float*)d_in[0];
  const int*   ei       = (const int*)d_in[1];
  const float* ea       = (const float*)d_in[2];
  const float* W        = (const float*)d_in[3];
  const float* W_edge   = (const float*)d_in[4];
  const float* att_src  = (const float*)d_in[5];
  const float* att_dst  = (const float*)d_in[6];
  const float* att_edge = (const float*)d_in[7];
  const float* bias     = (const float*)d_in[8];
  float* out = (float*)d_out;

  int N = in_sizes[0] / FIN;
  int E = in_sizes[1] / 2;
  int nb = (N + 255) / 256;

  char* ws = (char*)d_ws;
  auto take = [&](size_t bytes) {
    char* p = ws;
    ws += (bytes + 255) & ~(size_t)255;
    return p;
  };
  unsigned short* xhb    = (unsigned short*)take((size_t)N * HC * 2);
  float*          a_dst  = (float*)take((size_t)N * H * 4);
  unsigned short* a_srch = (unsigned short*)take((size_t)N * H * 2);
  unsigned short* recs16 = (unsigned short*)take((size_t)E * 16);
  int*            sarr   = (int*)take((size_t)E * 4);
  unsigned short* Whi    = (unsigned short*)take((size_t)HC * FIN * 2);
  unsigned short* Wlo    = (unsigned short*)take((size_t)HC * FIN * 2);
  int*            deg    = (int*)take((size_t)N * 4 + (size_t)N * H * 4);  // deg | aesum contiguous (one memset)
  float*          aesum  = (float*)(deg + N);
  int*            rowptr = (int*)take((size_t)(N + 1) * 4);
  int*            rank   = (int*)take((size_t)E * 4);
  int*            bsum   = (int*)take((size_t)nb * 4);

  hipMemsetAsync(deg, 0, (size_t)N * 4 + (size_t)N * H * 4, stream);
  k_deg<<<(E + 255) / 256, 256, 0, stream>>>(ei, deg, rank, W, Whi, Wlo, E);
  k_xh<<<dim3((N + 127) / 128, 2), 256, 0, stream>>>(x, Whi, Wlo, att_src, att_dst, xhb, a_dst, a_srch, N);
  k_scan1<<<nb, 256, 0, stream>>>(deg, bsum, N);
  k_scan23<<<nb, 256, 0, stream>>>(deg, bsum, rowptr, N, E, nb);
  k_edge_scatter<<<(E + 511) / 512, 256, 0, stream>>>(ei, ea, W_edge, att_edge, a_srch, rowptr, rank, recs16, sarr, aesum, E);
  k_node<<<(N + 3) / 4, 256, 0, stream>>>(xhb, a_srch, a_dst, recs16, sarr, rowptr, aesum, bias, out, N);
}

// Round 5
// 330.769 us; speedup vs baseline: 1.7884x; 1.7884x over previous
//
#include <hip/hip_runtime.h>
#include <hip/hip_fp16.h>
#include <math.h>

#define H 8
#define C 32
#define HC 256      // H*C
#define FE 16
#define FIN 128
#define NEG_SLOPE 0.2f

typedef __attribute__((ext_vector_type(8))) short bf16x8;
typedef __attribute__((ext_vector_type(4))) float f32x4;
typedef __attribute__((ext_vector_type(2))) float f32x2;

__device__ __forceinline__ unsigned short f2bf(float f) {
  unsigned int u = __float_as_uint(f);
  unsigned int lsb = (u >> 16) & 1u;
  u += 0x7fffu + lsb;               // round-to-nearest-even
  return (unsigned short)(u >> 16);
}
__device__ __forceinline__ float bf2f(unsigned short s) {
  return __uint_as_float(((unsigned int)s) << 16);
}
__device__ __forceinline__ unsigned short f2h(float f) {
  return __half_as_ushort(__float2half(f));
}
__device__ __forceinline__ float h2f(unsigned short s) {
  return __half2float(__ushort_as_half(s));
}
// packed 2xf32 FMA: acc = x*w + acc (bit-exact == 2 scalar fmaf)
__device__ __forceinline__ void pkfma(f32x2& acc, f32x2 x, f32x2 w) {
  asm volatile("v_pk_fma_f32 %0, %1, %2, %0" : "+v"(acc) : "v"(x), "v"(w));
}

// split 8 fp32 into hi (truncated bf16) + lo (RNE bf16 of residual)
__device__ __forceinline__ void split8(const float* v, bf16x8& hi, bf16x8& lo) {
#pragma unroll
  for (int i = 0; i < 8; ++i) {
    unsigned int u = __float_as_uint(v[i]);
    unsigned int hu = u & 0xffff0000u;
    float r = v[i] - __uint_as_float(hu);
    hi[i] = (short)(hu >> 16);
    lo[i] = (short)f2bf(r);
  }
}

// ---------------- xh^T = W @ x^T via MFMA split-bf16 (3 passes, fp32-grade accuracy) ----------------
__global__ __launch_bounds__(256) void k_xh(const float* __restrict__ x,
                                            const unsigned short* __restrict__ Whi,
                                            const unsigned short* __restrict__ Wlo,
                                            const float* __restrict__ att_src,
                                            const float* __restrict__ att_dst,
                                            unsigned short* __restrict__ xhb,
                                            float* __restrict__ a_dst,
                                            unsigned short* __restrict__ a_srch, int N) {
  int t = threadIdx.x;
  int w = t >> 6, lane = t & 63;
  int n15 = lane & 15, q = lane >> 4;
  int nodeBase = blockIdx.x * 128 + w * 32;      // + nt*16 + n15
  int chBase = blockIdx.y * 128;                 // + mt*16 + (row idx)

  f32x4 acc[8][2];
#pragma unroll
  for (int mt = 0; mt < 8; ++mt)
#pragma unroll
    for (int nt = 0; nt < 2; ++nt) acc[mt][nt] = (f32x4)(0.f);

  for (int ks = 0; ks < 4; ++ks) {
    int kOff = ks * 32 + q * 8;
    bf16x8 Bhi[2], Blo[2];
#pragma unroll
    for (int nt = 0; nt < 2; ++nt) {
      int node = nodeBase + nt * 16 + n15;
      int rn = (node < N) ? node : (N - 1);
      const float* px = &x[(size_t)rn * FIN + kOff];
      float vb[8];
      *(float4*)&vb[0] = *(const float4*)px;
      *(float4*)&vb[4] = *(const float4*)(px + 4);
      split8(vb, Bhi[nt], Blo[nt]);
    }
#pragma unroll
    for (int mt = 0; mt < 8; ++mt) {
      int widx = ((chBase + mt * 16 + n15) << 7) + kOff;
      bf16x8 Ahi = *(const bf16x8*)&Whi[widx];
      bf16x8 Alo = *(const bf16x8*)&Wlo[widx];
#pragma unroll
      for (int nt = 0; nt < 2; ++nt) {
        acc[mt][nt] = __builtin_amdgcn_mfma_f32_16x16x32_bf16(Ahi, Bhi[nt], acc[mt][nt], 0, 0, 0);
        acc[mt][nt] = __builtin_amdgcn_mfma_f32_16x16x32_bf16(Ahi, Blo[nt], acc[mt][nt], 0, 0, 0);
        acc[mt][nt] = __builtin_amdgcn_mfma_f32_16x16x32_bf16(Alo, Bhi[nt], acc[mt][nt], 0, 0, 0);
      }
    }
  }

  // Epilogue. C/D layout: col(lane&15)=node, row=q*4+reg = channel within tile.
  float ps[2][4] = {{0.f,0.f,0.f,0.f},{0.f,0.f,0.f,0.f}};
  float pd[2][4] = {{0.f,0.f,0.f,0.f},{0.f,0.f,0.f,0.f}};
#pragma unroll
  for (int mt = 0; mt < 8; ++mt) {
    int hl = mt >> 1;
#pragma unroll
    for (int r = 0; r < 4; ++r) {
      int ch = chBase + mt * 16 + q * 4 + r;
      float as_c = att_src[ch], ad_c = att_dst[ch];
#pragma unroll
      for (int nt = 0; nt < 2; ++nt) {
        float val = acc[mt][nt][r];
        ps[nt][hl] = fmaf(val, as_c, ps[nt][hl]);
        pd[nt][hl] = fmaf(val, ad_c, pd[nt][hl]);
      }
    }
#pragma unroll
    for (int nt = 0; nt < 2; ++nt) {
      int node = nodeBase + nt * 16 + n15;
      if (node < N) {
        ushort4 us;
        us.x = f2bf(acc[mt][nt][0]); us.y = f2bf(acc[mt][nt][1]);
        us.z = f2bf(acc[mt][nt][2]); us.w = f2bf(acc[mt][nt][3]);
        *(ushort4*)&xhb[(size_t)node * HC + chBase + mt * 16 + q * 4] = us;
      }
    }
  }
#pragma unroll
  for (int nt = 0; nt < 2; ++nt)
#pragma unroll
    for (int hl = 0; hl < 4; ++hl) {
      ps[nt][hl] += __shfl_xor(ps[nt][hl], 16, 64);
      ps[nt][hl] += __shfl_xor(ps[nt][hl], 32, 64);
      pd[nt][hl] += __shfl_xor(pd[nt][hl], 16, 64);
      pd[nt][hl] += __shfl_xor(pd[nt][hl], 32, 64);
    }
  if (q == 0) {
#pragma unroll
    for (int nt = 0; nt < 2; ++nt) {
      int node = nodeBase + nt * 16 + n15;
      if (node < N) {
        *(float4*)&a_dst[node * H + blockIdx.y * 4] = make_float4(pd[nt][0], pd[nt][1], pd[nt][2], pd[nt][3]);
        unsigned int p0 = (unsigned int)f2h(ps[nt][0]) | ((unsigned int)f2h(ps[nt][1]) << 16);
        unsigned int p1 = (unsigned int)f2h(ps[nt][2]) | ((unsigned int)f2h(ps[nt][3]) << 16);
        *(uint2*)&a_srch[(size_t)node * H + blockIdx.y * 4] = make_uint2(p0, p1);
      }
    }
  }
}

// ---------------- degree histogram + rank; also splits W into bf16 hi/lo (fused one-off) ----------------
__global__ __launch_bounds__(256) void k_deg(const int* __restrict__ ei,
                                             int* __restrict__ deg,
                                             int* __restrict__ rank,
                                             const float* __restrict__ W,
                                             unsigned short* __restrict__ Whi,
                                             unsigned short* __restrict__ Wlo, int E) {
  int e = blockIdx.x * 256 + threadIdx.x;
  if (e < HC * FIN) {
    float v = W[e];
    unsigned int u = __float_as_uint(v);
    unsigned int hu = u & 0xffff0000u;
    Whi[e] = (unsigned short)(hu >> 16);
    Wlo[e] = f2bf(v - __uint_as_float(hu));
  }
  if (e < E) rank[e] = atomicAdd(&deg[ei[E + e]], 1);
}

// ---------------- single-kernel exclusive scan via decoupled lookback ----------------
// st[b]: hi32 flag (0=none,1=aggregate,2=inclusive), lo32 value. Zeroed by host memset each launch.
// nb (<=~200) blocks are all co-resident on 256 CUs -> spin is deadlock-free.
__global__ __launch_bounds__(256) void k_scan(const int* __restrict__ deg,
                                              unsigned long long* __restrict__ st,
                                              int* __restrict__ rowptr, int N, int E) {
  __shared__ int buf[256];
  __shared__ int bofs_sh;
  int t = threadIdx.x, b = blockIdx.x;
  int i = b * 256 + t;
  int v = (i < N) ? deg[i] : 0;
  buf[t] = v;
  __syncthreads();
  for (int off = 1; off < 256; off <<= 1) {
    int y = (t >= off) ? buf[t - off] : 0;
    __syncthreads();
    buf[t] += y;
    __syncthreads();
  }
  if (t == 0) {
    int agg = buf[255];
    if (b == 0) {
      __hip_atomic_store(&st[0], (2ull << 32) | (unsigned int)agg, __ATOMIC_RELEASE, __HIP_MEMORY_SCOPE_AGENT);
      bofs_sh = 0;
    } else {
      __hip_atomic_store(&st[b], (1ull << 32) | (unsigned int)agg, __ATOMIC_RELEASE, __HIP_MEMORY_SCOPE_AGENT);
      int excl = 0;
      int p = b - 1;
      while (true) {
        unsigned long long s = __hip_atomic_load(&st[p], __ATOMIC_ACQUIRE, __HIP_MEMORY_SCOPE_AGENT);
        unsigned int flag = (unsigned int)(s >> 32);
        if (flag == 0u) { __builtin_amdgcn_s_sleep(1); continue; }
        excl += (int)(unsigned int)(s & 0xffffffffull);
        if (flag == 2u) break;
        --p;
      }
      __hip_atomic_store(&st[b], (2ull << 32) | (unsigned int)(excl + agg), __ATOMIC_RELEASE, __HIP_MEMORY_SCOPE_AGENT);
      bofs_sh = excl;
    }
  }
  __syncthreads();
  if (i < N) rowptr[i] = bofs_sh + buf[t] - v;
  if (i == 0) rowptr[N] = E;
}

// ---------------- per-edge (2 edges/thread): a_edge = ea @ M; fold fp16 a_src[src] into record ----------------
// record[pos] = 8 x uint32: lo16 = fp16(a_edge + a_src[src][h]), hi16 = fp16(a_edge)
__global__ __launch_bounds__(256) void k_edge_scatter(const int* __restrict__ ei,
                                                      const float* __restrict__ ea,
                                                      const float* __restrict__ W_edge,
                                                      const float* __restrict__ att_edge,
                                                      const unsigned short* __restrict__ a_srch,
                                                      const int* __restrict__ rowptr,
                                                      const int* __restrict__ rank,
                                                      unsigned int* __restrict__ recs,
                                                      int* __restrict__ sarr, int E) {
  __shared__ float Ms[FE * H];
  int t = threadIdx.x;
  if (t < FE * H) {          // M[f][h] = sum_c W_edge[(h*C+c)*FE+f] * att_edge[h*C+c]
    int f = t >> 3, h = t & 7;
    float acc = 0.f;
#pragma unroll
    for (int c = 0; c < C; ++c)
      acc += W_edge[(h * C + c) * FE + f] * att_edge[h * C + c];
    Ms[f * H + h] = acc;
  }
  __syncthreads();
  int e0 = blockIdx.x * 512 + t;
  int e1 = e0 + 256;
  bool va = (e0 < E), vb = (e1 < E);
  int ca = va ? e0 : 0, cb = vb ? e1 : 0;
  // ---- independent loads first (2 chains in flight) ----
  int s0 = ei[ca], d0 = ei[E + ca];
  int s1 = ei[cb], d1 = ei[E + cb];
  const float4* pA = (const float4*)&ea[(size_t)ca * FE];
  const float4* pB = (const float4*)&ea[(size_t)cb * FE];
  float4 A0 = pA[0], A1 = pA[1], A2 = pA[2], A3 = pA[3];
  float4 B0 = pB[0], B1 = pB[1], B2 = pB[2], B3 = pB[3];
  int rk0 = rank[ca], rk1 = rank[cb];
  // ---- one dependent hop, both chains issued together ----
  int rp0 = rowptr[d0], rp1 = rowptr[d1];
  uint4 asA = *(const uint4*)&a_srch[(size_t)s0 * H];
  uint4 asB = *(const uint4*)&a_srch[(size_t)s1 * H];

  float eavA[FE] = {A0.x, A0.y, A0.z, A0.w, A1.x, A1.y, A1.z, A1.w,
                    A2.x, A2.y, A2.z, A2.w, A3.x, A3.y, A3.z, A3.w};
  float eavB[FE] = {B0.x, B0.y, B0.z, B0.w, B1.x, B1.y, B1.z, B1.w,
                    B2.x, B2.y, B2.z, B2.w, B3.x, B3.y, B3.z, B3.w};
  float oA[H], oB[H];
#pragma unroll
  for (int h = 0; h < H; ++h) {
    float aa = 0.f, ab = 0.f;
#pragma unroll
    for (int f = 0; f < FE; ++f) {
      float m = Ms[f * H + h];
      aa += eavA[f] * m;
      ab += eavB[f] * m;
    }
    oA[h] = aa; oB[h] = ab;
  }
  unsigned int asw[2][4] = {{asA.x, asA.y, asA.z, asA.w}, {asB.x, asB.y, asB.z, asB.w}};
  if (va) {
    int pos = rp0 + rk0;
    unsigned int rec[H];
#pragma unroll
    for (int h = 0; h < H; ++h) {
      float asv = h2f((unsigned short)((h & 1) ? (asw[0][h >> 1] >> 16) : (asw[0][h >> 1] & 0xffffu)));
      rec[h] = (unsigned int)f2h(oA[h] + asv) | ((unsigned int)f2h(oA[h]) << 16);
    }
    uint4* rp = (uint4*)&recs[(size_t)pos * 8];
    rp[0] = make_uint4(rec[0], rec[1], rec[2], rec[3]);
    rp[1] = make_uint4(rec[4], rec[5], rec[6], rec[7]);
    sarr[pos] = s0;
  }
  if (vb) {
    int pos = rp1 + rk1;
    unsigned int rec[H];
#pragma unroll
    for (int h = 0; h < H; ++h) {
      float asv = h2f((unsigned short)((h & 1) ? (asw[1][h >> 1] >> 16) : (asw[1][h >> 1] & 0xffffu)));
      rec[h] = (unsigned int)f2h(oB[h] + asv) | ((unsigned int)f2h(oB[h]) << 16);
    }
    uint4* rp = (uint4*)&recs[(size_t)pos * 8];
    rp[0] = make_uint4(rec[0], rec[1], rec[2], rec[3]);
    rp[1] = make_uint4(rec[4], rec[5], rec[6], rec[7]);
    sarr[pos] = s1;
  }
}

// ---------------- wave-per-node: max-free single-pass softmax + pk_fma paired gather ----------------
// exp(alpha)/sum(exp(alpha)) == reference's max-shifted softmax; |alpha| <~ 12 so fp32 exp is safe.
// wlds layout pair-interleaved: idx = (j>>1)*16 + h*2 + (j&1), so a ds_read_b64 yields {w_j, w_j+1}.
__global__ __launch_bounds__(256) void k_node(const unsigned short* __restrict__ xhb,
                                              const unsigned short* __restrict__ a_srch,
                                              const float* __restrict__ a_dst,
                                              const unsigned int* __restrict__ recs,
                                              const int* __restrict__ sarr,
                                              const int* __restrict__ rowptr,
                                              const float* __restrict__ bias,
                                              float* __restrict__ out, int N) {
  __shared__ float wlds[4][512];   // pair-interleaved, j<64
  __shared__ int   slds[4][64];
  int wv = threadIdx.x >> 6;
  int lane = threadIdx.x & 63;
  int n = blockIdx.x * 4 + wv;
  if (n >= N) return;
  int start = rowptr[n];
  int deg = rowptr[n + 1] - start;
  int jmax = (deg < 64) ? deg : 64;
  int nit = (jmax + 7) >> 3;           // live 8-edge chunks (wave-uniform -> scalar branch)
  int padded = nit << 3;
  int h = lane & 7, esub = lane >> 3;
  float adst = a_dst[n * H + h];
  float asrc = h2f(a_srch[(size_t)n * H + h]);

  // src list -> LDS in ONE coalesced load; pad rows point at self (weight 0 in wlds)
  if (lane < padded) slds[wv][lane] = (lane < jmax) ? sarr[start + lane] : n;

  // ---- phase 1a: batch all record loads (no uses in between) ----
  const unsigned int* rb = recs + (size_t)start * 8 + lane;
  unsigned int u[8] = {0, 0, 0, 0, 0, 0, 0, 0};
#pragma unroll
  for (int it = 0; it < 8; ++it)
    if (it < nit) {
      int j = it * 8 + esub;
      if (j < jmax) u[it] = rb[it * 64];
    }

  // ---- phase 1b: w = exp(alpha) directly (no max pass); raw-ae sum for self loop ----
  int widx = ((esub >> 1) << 4) + (h << 1) + (esub & 1);   // pair-interleaved slot for edge j=it*8+esub
  float den = 0.f, psum = 0.f;
#pragma unroll
  for (int it = 0; it < 8; ++it)
    if (it < nit) {
      int j = it * 8 + esub;
      bool val = (j < jmax);
      float raw = h2f((unsigned short)(u[it] >> 16));                 // raw a_edge (0 when padded)
      float a = h2f((unsigned short)(u[it] & 0xffffu)) + adst;        // a_edge + a_src + a_dst
      a = fmaxf(a, NEG_SLOPE * a);                                    // leaky relu (slope<1)
      float w = val ? __expf(a) : 0.f;
      psum += val ? raw : 0.f;
      den += w;
      wlds[wv][it * 64 + widx] = w;     // zero-pad falls out naturally
    }
  for (int j0 = 64; j0 < deg; j0 += 8) {   // overflow deg>64 (rare)
    int j = j0 + esub;
    if (j < deg) {
      unsigned int t2 = recs[(size_t)(start + j) * 8 + h];
      psum += h2f((unsigned short)(t2 >> 16));
      float a = h2f((unsigned short)(t2 & 0xffffu)) + adst;
      a = fmaxf(a, NEG_SLOPE * a);
      den += __expf(a);
    }
  }
#pragma unroll
  for (int m = 8; m <= 32; m <<= 1) {
    den += __shfl_xor(den, m, 64);
    psum += __shfl_xor(psum, m, 64);
  }
  float aself = asrc + adst + psum / fmaxf((float)deg, 1.f);
  aself = fmaxf(aself, NEG_SLOPE * aself);
  float wself = __expf(aself);
  float inv = 1.f / (den + wself);

  // ---- phase 2: guard-free gather, edge-paired v_pk_fma_f32 accumulation ----
  int hc = lane >> 3;
  float inv_c  = __shfl(inv, hc, 64);
  float ws_c   = __shfl(wself, hc, 64);
  float adst_c = __shfl(adst, hc, 64);
  f32x2 A0, A1, A2, A3;
  {
    uint2 su = ((const uint2*)(xhb + (((size_t)n) << 8)))[lane];
    A0[0] = ws_c * __uint_as_float(su.x << 16);         A0[1] = 0.f;
    A1[0] = ws_c * __uint_as_float(su.x & 0xffff0000u); A1[1] = 0.f;
    A2[0] = ws_c * __uint_as_float(su.y << 16);         A2[1] = 0.f;
    A3[0] = ws_c * __uint_as_float(su.y & 0xffff0000u); A3[1] = 0.f;
  }
  for (int j0 = 0; j0 < padded; j0 += 8) {
    uint2 v[8];
#pragma unroll
    for (int k = 0; k < 8; ++k)
      v[k] = ((const uint2*)(xhb + (((size_t)slds[wv][j0 + k]) << 8)))[lane];
    // weight pairs {w_j, w_j+1}: one 8B LDS read each (idx = j0*8 + k2*16 + hc*2, 8B-aligned)
#pragma unroll
    for (int k2 = 0; k2 < 4; ++k2) {
      f32x2 wp = *(const f32x2*)&wlds[wv][j0 * 8 + k2 * 16 + hc * 2];
      uint2 va = v[2 * k2], vb2 = v[2 * k2 + 1];
      f32x2 p;
      p[0] = __uint_as_float(va.x << 16);          p[1] = __uint_as_float(vb2.x << 16);
      pkfma(A0, p, wp);
      p[0] = __uint_as_float(va.x & 0xffff0000u);  p[1] = __uint_as_float(vb2.x & 0xffff0000u);
      pkfma(A1, p, wp);
      p[0] = __uint_as_float(va.y << 16);          p[1] = __uint_as_float(vb2.y << 16);
      pkfma(A2, p, wp);
      p[0] = __uint_as_float(va.y & 0xffff0000u);  p[1] = __uint_as_float(vb2.y & 0xffff0000u);
      pkfma(A3, p, wp);
    }
  }
  float accx = A0[0] + A0[1];
  float accy = A1[0] + A1[1];
  float accz = A2[0] + A2[1];
  float accw = A3[0] + A3[1];
  for (int j = 64; j < deg; ++j) {       // overflow: recompute weight from record
    int src = sarr[start + j];
    unsigned int t2 = recs[(size_t)(start + j) * 8 + hc];
    float a = h2f((unsigned short)(t2 & 0xffffu)) + adst_c;
    a = fmaxf(a, NEG_SLOPE * a);
    float wj = __expf(a);
    uint2 v = ((const uint2*)(xhb + (((size_t)src) << 8)))[lane];
    accx = fmaf(__uint_as_float(v.x << 16), wj, accx);
    accy = fmaf(__uint_as_float(v.x & 0xffff0000u), wj, accy);
    accz = fmaf(__uint_as_float(v.y << 16), wj, accz);
    accw = fmaf(__uint_as_float(v.y & 0xffff0000u), wj, accw);
  }
  accx *= inv_c; accy *= inv_c; accz *= inv_c; accw *= inv_c;

  // head mean across hc (xor 8,16,32)
#pragma unroll
  for (int m = 8; m <= 32; m <<= 1) {
    accx += __shfl_xor(accx, m, 64);
    accy += __shfl_xor(accy, m, 64);
    accz += __shfl_xor(accz, m, 64);
    accw += __shfl_xor(accw, m, 64);
  }
  if (lane < 8) {
    float4 b = ((const float4*)bias)[lane];
    float4 o;
    o.x = accx * 0.125f + b.x;
    o.y = accy * 0.125f + b.y;
    o.z = accz * 0.125f + b.z;
    o.w = accw * 0.125f + b.w;
    ((float4*)&out[(size_t)n * C])[lane] = o;
  }
}

extern "C" void kernel_launch(void* const* d_in, const int* in_sizes, int n_in,
                              void* d_out, int out_size, void* d_ws, size_t ws_size,
                              hipStream_t stream) {
  const float* x        = (const float*)d_in[0];
  const int*   ei       = (const int*)d_in[1];
  const float* ea       = (const float*)d_in[2];
  const float* W        = (const float*)d_in[3];
  const float* W_edge   = (const float*)d_in[4];
  const float* att_src  = (const float*)d_in[5];
  const float* att_dst  = (const float*)d_in[6];
  const float* att_edge = (const float*)d_in[7];
  const float* bias     = (const float*)d_in[8];
  float* out = (float*)d_out;

  int N = in_sizes[0] / FIN;
  int E = in_sizes[1] / 2;
  int nb = (N + 255) / 256;

  char* ws = (char*)d_ws;
  auto take = [&](size_t bytes) {
    char* p = ws;
    ws += (bytes + 255) & ~(size_t)255;
    return p;
  };
  unsigned short* xhb    = (unsigned short*)take((size_t)N * HC * 2);
  float*          a_dst  = (float*)take((size_t)N * H * 4);
  unsigned short* a_srch = (unsigned short*)take((size_t)N * H * 2);
  unsigned int*   recs   = (unsigned int*)take((size_t)E * 32);
  int*            sarr   = (int*)take((size_t)E * 4);
  unsigned short* Whi    = (unsigned short*)take((size_t)HC * FIN * 2);
  unsigned short* Wlo    = (unsigned short*)take((size_t)HC * FIN * 2);
  size_t degBytes = ((size_t)N * 4 + 7) & ~(size_t)7;
  char*  zbase    = take(degBytes + (size_t)nb * 8);     // deg | lookback status, one memset
  int*            deg    = (int*)zbase;
  unsigned long long* st = (unsigned long long*)(zbase + degBytes);
  int*            rowptr = (int*)take((size_t)(N + 1) * 4);
  int*            rank   = (int*)take((size_t)E * 4);

  hipMemsetAsync(zbase, 0, degBytes + (size_t)nb * 8, stream);
  k_deg<<<(E + 255) / 256, 256, 0, stream>>>(ei, deg, rank, W, Whi, Wlo, E);
  k_xh<<<dim3((N + 127) / 128, 2), 256, 0, stream>>>(x, Whi, Wlo, att_src, att_dst, xhb, a_dst, a_srch, N);
  k_scan<<<nb, 256, 0, stream>>>(deg, st, rowptr, N, E);
  k_edge_scatter<<<(E + 511) / 512, 256, 0, stream>>>(ei, ea, W_edge, att_edge, a_srch, rowptr, rank, recs, sarr, E);
  k_node<<<(N + 3) / 4, 256, 0, stream>>>(xhb, a_srch, a_dst, recs, sarr, rowptr, bias, out, N);
}

// Round 6
// 299.567 us; speedup vs baseline: 1.9747x; 1.1042x over previous
//
#include <hip/hip_runtime.h>
#include <hip/hip_fp16.h>
#include <math.h>

#define H 8
#define C 32
#define HC 256      // H*C
#define FE 16
#define FIN 128
#define NEG_SLOPE 0.2f

typedef __attribute__((ext_vector_type(8))) short bf16x8;
typedef __attribute__((ext_vector_type(4))) float f32x4;
typedef __attribute__((ext_vector_type(2))) float f32x2;

__device__ __forceinline__ unsigned short f2bf(float f) {
  unsigned int u = __float_as_uint(f);
  unsigned int lsb = (u >> 16) & 1u;
  u += 0x7fffu + lsb;               // round-to-nearest-even
  return (unsigned short)(u >> 16);
}
__device__ __forceinline__ float bf2f(unsigned short s) {
  return __uint_as_float(((unsigned int)s) << 16);
}
__device__ __forceinline__ unsigned short f2h(float f) {
  return __half_as_ushort(__float2half(f));
}
__device__ __forceinline__ float h2f(unsigned short s) {
  return __half2float(__ushort_as_half(s));
}
// packed 2xf32 FMA: acc = x*w + acc (bit-exact == 2 scalar fmaf)
__device__ __forceinline__ void pkfma(f32x2& acc, f32x2 x, f32x2 w) {
  asm volatile("v_pk_fma_f32 %0, %1, %2, %0" : "+v"(acc) : "v"(x), "v"(w));
}

// split 8 fp32 into hi (truncated bf16) + lo (RNE bf16 of residual)
__device__ __forceinline__ void split8(const float* v, bf16x8& hi, bf16x8& lo) {
#pragma unroll
  for (int i = 0; i < 8; ++i) {
    unsigned int u = __float_as_uint(v[i]);
    unsigned int hu = u & 0xffff0000u;
    float r = v[i] - __uint_as_float(hu);
    hi[i] = (short)(hu >> 16);
    lo[i] = (short)f2bf(r);
  }
}

// ---------------- FUSED: edge-degree histogram (first nde blocks) + xh GEMM (rest) ----------------
// deg path and xh path are independent: xh splits W inline (same bytes as Whi+Wlo reads).
// Latency-bound histogram hides under the MFMA GEMM.
__global__ __launch_bounds__(256) void k_fused(const float* __restrict__ x,
                                               const float* __restrict__ W,
                                               const float* __restrict__ att_src,
                                               const float* __restrict__ att_dst,
                                               const int* __restrict__ ei,
                                               int* __restrict__ deg,
                                               int* __restrict__ rank,
                                               unsigned short* __restrict__ xhb,
                                               float* __restrict__ a_dst,
                                               unsigned short* __restrict__ a_srch,
                                               int N, int E, int nde, int nx) {
  int t = threadIdx.x;
  if ((int)blockIdx.x < nde) {
    // ---------- degree histogram path ----------
    int e = blockIdx.x * 256 + t;
    if (e < E) rank[e] = atomicAdd(&deg[ei[E + e]], 1);
    return;
  }
  // ---------- xh GEMM path ----------
  int bb = blockIdx.x - nde;
  int by = (bb >= nx) ? 1 : 0;
  int bx = bb - by * nx;

  int w = t >> 6, lane = t & 63;
  int n15 = lane & 15, q = lane >> 4;
  int nodeBase = bx * 128 + w * 32;      // + nt*16 + n15
  int chBase = by * 128;                 // + mt*16 + (row idx)

  f32x4 acc[8][2];
#pragma unroll
  for (int mt = 0; mt < 8; ++mt)
#pragma unroll
    for (int nt = 0; nt < 2; ++nt) acc[mt][nt] = (f32x4)(0.f);

  for (int ks = 0; ks < 4; ++ks) {
    int kOff = ks * 32 + q * 8;
    bf16x8 Bhi[2], Blo[2];
#pragma unroll
    for (int nt = 0; nt < 2; ++nt) {
      int node = nodeBase + nt * 16 + n15;
      int rn = (node < N) ? node : (N - 1);
      const float* px = &x[(size_t)rn * FIN + kOff];
      float vb[8];
      *(float4*)&vb[0] = *(const float4*)px;
      *(float4*)&vb[4] = *(const float4*)(px + 4);
      split8(vb, Bhi[nt], Blo[nt]);
    }
#pragma unroll
    for (int mt = 0; mt < 8; ++mt) {
      int widx = ((chBase + mt * 16 + n15) << 7) + kOff;
      const float* pw = &W[widx];
      float wv8[8];
      *(float4*)&wv8[0] = *(const float4*)pw;
      *(float4*)&wv8[4] = *(const float4*)(pw + 4);
      bf16x8 Ahi, Alo;
      split8(wv8, Ahi, Alo);
#pragma unroll
      for (int nt = 0; nt < 2; ++nt) {
        acc[mt][nt] = __builtin_amdgcn_mfma_f32_16x16x32_bf16(Ahi, Bhi[nt], acc[mt][nt], 0, 0, 0);
        acc[mt][nt] = __builtin_amdgcn_mfma_f32_16x16x32_bf16(Ahi, Blo[nt], acc[mt][nt], 0, 0, 0);
        acc[mt][nt] = __builtin_amdgcn_mfma_f32_16x16x32_bf16(Alo, Bhi[nt], acc[mt][nt], 0, 0, 0);
      }
    }
  }

  // Epilogue. C/D layout: col(lane&15)=node, row=q*4+reg = channel within tile.
  float ps[2][4] = {{0.f,0.f,0.f,0.f},{0.f,0.f,0.f,0.f}};
  float pd[2][4] = {{0.f,0.f,0.f,0.f},{0.f,0.f,0.f,0.f}};
#pragma unroll
  for (int mt = 0; mt < 8; ++mt) {
    int hl = mt >> 1;
#pragma unroll
    for (int r = 0; r < 4; ++r) {
      int ch = chBase + mt * 16 + q * 4 + r;
      float as_c = att_src[ch], ad_c = att_dst[ch];
#pragma unroll
      for (int nt = 0; nt < 2; ++nt) {
        float val = acc[mt][nt][r];
        ps[nt][hl] = fmaf(val, as_c, ps[nt][hl]);
        pd[nt][hl] = fmaf(val, ad_c, pd[nt][hl]);
      }
    }
#pragma unroll
    for (int nt = 0; nt < 2; ++nt) {
      int node = nodeBase + nt * 16 + n15;
      if (node < N) {
        ushort4 us;
        us.x = f2bf(acc[mt][nt][0]); us.y = f2bf(acc[mt][nt][1]);
        us.z = f2bf(acc[mt][nt][2]); us.w = f2bf(acc[mt][nt][3]);
        *(ushort4*)&xhb[(size_t)node * HC + chBase + mt * 16 + q * 4] = us;
      }
    }
  }
#pragma unroll
  for (int nt = 0; nt < 2; ++nt)
#pragma unroll
    for (int hl = 0; hl < 4; ++hl) {
      ps[nt][hl] += __shfl_xor(ps[nt][hl], 16, 64);
      ps[nt][hl] += __shfl_xor(ps[nt][hl], 32, 64);
      pd[nt][hl] += __shfl_xor(pd[nt][hl], 16, 64);
      pd[nt][hl] += __shfl_xor(pd[nt][hl], 32, 64);
    }
  if (q == 0) {
#pragma unroll
    for (int nt = 0; nt < 2; ++nt) {
      int node = nodeBase + nt * 16 + n15;
      if (node < N) {
        *(float4*)&a_dst[node * H + by * 4] = make_float4(pd[nt][0], pd[nt][1], pd[nt][2], pd[nt][3]);
        unsigned int p0 = (unsigned int)f2h(ps[nt][0]) | ((unsigned int)f2h(ps[nt][1]) << 16);
        unsigned int p1 = (unsigned int)f2h(ps[nt][2]) | ((unsigned int)f2h(ps[nt][3]) << 16);
        *(uint2*)&a_srch[(size_t)node * H + by * 4] = make_uint2(p0, p1);
      }
    }
  }
}

// ---------------- scan stage 1: per-block sums ----------------
__global__ __launch_bounds__(256) void k_scan1(const int* __restrict__ deg,
                                               int* __restrict__ bsum, int N) {
  int t = threadIdx.x;
  int i = blockIdx.x * 256 + t;
  int v = (i < N) ? deg[i] : 0;
#pragma unroll
  for (int m = 1; m < 64; m <<= 1) v += __shfl_xor(v, m, 64);
  __shared__ int wsum[4];
  if ((t & 63) == 0) wsum[t >> 6] = v;
  __syncthreads();
  if (t == 0) bsum[blockIdx.x] = wsum[0] + wsum[1] + wsum[2] + wsum[3];
}

// ---------------- scan stage 2+3 fused: every block scans bsum in LDS, then local scan ----------------
__global__ __launch_bounds__(256) void k_scan23(const int* __restrict__ deg,
                                                const int* __restrict__ bsum,
                                                int* __restrict__ rowptr, int N, int E, int nb) {
  __shared__ int sb[256];
  __shared__ int buf[256];
  int t = threadIdx.x;
  sb[t] = (t < nb) ? bsum[t] : 0;
  int i = blockIdx.x * 256 + t;
  int v = (i < N) ? deg[i] : 0;
  buf[t] = v;
  __syncthreads();
  for (int off = 1; off < 256; off <<= 1) {
    int y1 = (t >= off) ? sb[t - off] : 0;
    int y2 = (t >= off) ? buf[t - off] : 0;
    __syncthreads();
    sb[t] += y1;
    buf[t] += y2;
    __syncthreads();
  }
  int bofs = (blockIdx.x == 0) ? 0 : sb[blockIdx.x - 1];
  if (i < N) rowptr[i] = bofs + buf[t] - v;
  if (i == 0) rowptr[N] = E;
}

// ---------------- per-edge (2 edges/thread): a_edge = ea @ M; fold fp16 a_src[src] into record ----------------
// record[pos] = 8 x uint32: lo16 = fp16(a_edge + a_src[src][h]), hi16 = fp16(a_edge)
__global__ __launch_bounds__(256) void k_edge_scatter(const int* __restrict__ ei,
                                                      const float* __restrict__ ea,
                                                      const float* __restrict__ W_edge,
                                                      const float* __restrict__ att_edge,
                                                      const unsigned short* __restrict__ a_srch,
                                                      const int* __restrict__ rowptr,
                                                      const int* __restrict__ rank,
                                                      unsigned int* __restrict__ recs,
                                                      int* __restrict__ sarr, int E) {
  __shared__ float Ms[FE * H];
  int t = threadIdx.x;
  if (t < FE * H) {          // M[f][h] = sum_c W_edge[(h*C+c)*FE+f] * att_edge[h*C+c]
    int f = t >> 3, h = t & 7;
    float acc = 0.f;
#pragma unroll
    for (int c = 0; c < C; ++c)
      acc += W_edge[(h * C + c) * FE + f] * att_edge[h * C + c];
    Ms[f * H + h] = acc;
  }
  __syncthreads();
  int e0 = blockIdx.x * 512 + t;
  int e1 = e0 + 256;
  bool va = (e0 < E), vb = (e1 < E);
  int ca = va ? e0 : 0, cb = vb ? e1 : 0;
  // ---- independent loads first (2 chains in flight) ----
  int s0 = ei[ca], d0 = ei[E + ca];
  int s1 = ei[cb], d1 = ei[E + cb];
  const float4* pA = (const float4*)&ea[(size_t)ca * FE];
  const float4* pB = (const float4*)&ea[(size_t)cb * FE];
  float4 A0 = pA[0], A1 = pA[1], A2 = pA[2], A3 = pA[3];
  float4 B0 = pB[0], B1 = pB[1], B2 = pB[2], B3 = pB[3];
  int rk0 = rank[ca], rk1 = rank[cb];
  // ---- one dependent hop, both chains issued together ----
  int rp0 = rowptr[d0], rp1 = rowptr[d1];
  uint4 asA = *(const uint4*)&a_srch[(size_t)s0 * H];
  uint4 asB = *(const uint4*)&a_srch[(size_t)s1 * H];

  float eavA[FE] = {A0.x, A0.y, A0.z, A0.w, A1.x, A1.y, A1.z, A1.w,
                    A2.x, A2.y, A2.z, A2.w, A3.x, A3.y, A3.z, A3.w};
  float eavB[FE] = {B0.x, B0.y, B0.z, B0.w, B1.x, B1.y, B1.z, B1.w,
                    B2.x, B2.y, B2.z, B2.w, B3.x, B3.y, B3.z, B3.w};
  float oA[H], oB[H];
#pragma unroll
  for (int h = 0; h < H; ++h) {
    float aa = 0.f, ab = 0.f;
#pragma unroll
    for (int f = 0; f < FE; ++f) {
      float m = Ms[f * H + h];
      aa += eavA[f] * m;
      ab += eavB[f] * m;
    }
    oA[h] = aa; oB[h] = ab;
  }
  unsigned int asw[2][4] = {{asA.x, asA.y, asA.z, asA.w}, {asB.x, asB.y, asB.z, asB.w}};
  if (va) {
    int pos = rp0 + rk0;
    unsigned int rec[H];
#pragma unroll
    for (int h = 0; h < H; ++h) {
      float asv = h2f((unsigned short)((h & 1) ? (asw[0][h >> 1] >> 16) : (asw[0][h >> 1] & 0xffffu)));
      rec[h] = (unsigned int)f2h(oA[h] + asv) | ((unsigned int)f2h(oA[h]) << 16);
    }
    uint4* rp = (uint4*)&recs[(size_t)pos * 8];
    rp[0] = make_uint4(rec[0], rec[1], rec[2], rec[3]);
    rp[1] = make_uint4(rec[4], rec[5], rec[6], rec[7]);
    sarr[pos] = s0;
  }
  if (vb) {
    int pos = rp1 + rk1;
    unsigned int rec[H];
#pragma unroll
    for (int h = 0; h < H; ++h) {
      float asv = h2f((unsigned short)((h & 1) ? (asw[1][h >> 1] >> 16) : (asw[1][h >> 1] & 0xffffu)));
      rec[h] = (unsigned int)f2h(oB[h] + asv) | ((unsigned int)f2h(oB[h]) << 16);
    }
    uint4* rp = (uint4*)&recs[(size_t)pos * 8];
    rp[0] = make_uint4(rec[0], rec[1], rec[2], rec[3]);
    rp[1] = make_uint4(rec[4], rec[5], rec[6], rec[7]);
    sarr[pos] = s1;
  }
}

// ---------------- wave-per-node: max-free single-pass softmax + pk_fma paired gather ----------------
// exp(alpha)/sum(exp(alpha)) == reference's max-shifted softmax; |alpha| <~ 12 so fp32 exp is safe.
// wlds layout pair-interleaved: idx = (j>>1)*16 + h*2 + (j&1), so a ds_read_b64 yields {w_j, w_j+1}.
__global__ __launch_bounds__(256) void k_node(const unsigned short* __restrict__ xhb,
                                              const unsigned short* __restrict__ a_srch,
                                              const float* __restrict__ a_dst,
                                              const unsigned int* __restrict__ recs,
                                              const int* __restrict__ sarr,
                                              const int* __restrict__ rowptr,
                                              const float* __restrict__ bias,
                                              float* __restrict__ out, int N) {
  __shared__ float wlds[4][512];   // pair-interleaved, j<64
  __shared__ int   slds[4][64];
  int wv = threadIdx.x >> 6;
  int lane = threadIdx.x & 63;
  int n = blockIdx.x * 4 + wv;
  if (n >= N) return;
  int start = rowptr[n];
  int deg = rowptr[n + 1] - start;
  int jmax = (deg < 64) ? deg : 64;
  int nit = (jmax + 7) >> 3;           // live 8-edge chunks (wave-uniform -> scalar branch)
  int padded = nit << 3;
  int h = lane & 7, esub = lane >> 3;
  float adst = a_dst[n * H + h];
  float asrc = h2f(a_srch[(size_t)n * H + h]);

  // src list -> LDS in ONE coalesced load; pad rows point at self (weight 0 in wlds)
  if (lane < padded) slds[wv][lane] = (lane < jmax) ? sarr[start + lane] : n;

  // ---- phase 1a: batch all record loads (no uses in between) ----
  const unsigned int* rb = recs + (size_t)start * 8 + lane;
  unsigned int u[8] = {0, 0, 0, 0, 0, 0, 0, 0};
#pragma unroll
  for (int it = 0; it < 8; ++it)
    if (it < nit) {
      int j = it * 8 + esub;
      if (j < jmax) u[it] = rb[it * 64];
    }

  // ---- phase 1b: w = exp(alpha) directly (no max pass); raw-ae sum for self loop ----
  int widx = ((esub >> 1) << 4) + (h << 1) + (esub & 1);   // pair-interleaved slot for edge j=it*8+esub
  float den = 0.f, psum = 0.f;
#pragma unroll
  for (int it = 0; it < 8; ++it)
    if (it < nit) {
      int j = it * 8 + esub;
      bool val = (j < jmax);
      float raw = h2f((unsigned short)(u[it] >> 16));                 // raw a_edge (0 when padded)
      float a = h2f((unsigned short)(u[it] & 0xffffu)) + adst;        // a_edge + a_src + a_dst
      a = fmaxf(a, NEG_SLOPE * a);                                    // leaky relu (slope<1)
      float w = val ? __expf(a) : 0.f;
      psum += val ? raw : 0.f;
      den += w;
      wlds[wv][it * 64 + widx] = w;     // zero-pad falls out naturally
    }
  for (int j0 = 64; j0 < deg; j0 += 8) {   // overflow deg>64 (rare)
    int j = j0 + esub;
    if (j < deg) {
      unsigned int t2 = recs[(size_t)(start + j) * 8 + h];
      psum += h2f((unsigned short)(t2 >> 16));
      float a = h2f((unsigned short)(t2 & 0xffffu)) + adst;
      a = fmaxf(a, NEG_SLOPE * a);
      den += __expf(a);
    }
  }
#pragma unroll
  for (int m = 8; m <= 32; m <<= 1) {
    den += __shfl_xor(den, m, 64);
    psum += __shfl_xor(psum, m, 64);
  }
  float aself = asrc + adst + psum / fmaxf((float)deg, 1.f);
  aself = fmaxf(aself, NEG_SLOPE * aself);
  float wself = __expf(aself);
  float inv = 1.f / (den + wself);

  // ---- phase 2: guard-free gather, edge-paired v_pk_fma_f32 accumulation ----
  int hc = lane >> 3;
  float inv_c  = __shfl(inv, hc, 64);
  float ws_c   = __shfl(wself, hc, 64);
  float adst_c = __shfl(adst, hc, 64);
  f32x2 A0, A1, A2, A3;
  {
    uint2 su = ((const uint2*)(xhb + (((size_t)n) << 8)))[lane];
    A0[0] = ws_c * __uint_as_float(su.x << 16);         A0[1] = 0.f;
    A1[0] = ws_c * __uint_as_float(su.x & 0xffff0000u); A1[1] = 0.f;
    A2[0] = ws_c * __uint_as_float(su.y << 16);         A2[1] = 0.f;
    A3[0] = ws_c * __uint_as_float(su.y & 0xffff0000u); A3[1] = 0.f;
  }
  for (int j0 = 0; j0 < padded; j0 += 8) {
    uint2 v[8];
#pragma unroll
    for (int k = 0; k < 8; ++k)
      v[k] = ((const uint2*)(xhb + (((size_t)slds[wv][j0 + k]) << 8)))[lane];
    // weight pairs {w_j, w_j+1}: one 8B LDS read each (idx = j0*8 + k2*16 + hc*2, 8B-aligned)
#pragma unroll
    for (int k2 = 0; k2 < 4; ++k2) {
      f32x2 wp = *(const f32x2*)&wlds[wv][j0 * 8 + k2 * 16 + hc * 2];
      uint2 va = v[2 * k2], vb2 = v[2 * k2 + 1];
      f32x2 p;
      p[0] = __uint_as_float(va.x << 16);          p[1] = __uint_as_float(vb2.x << 16);
      pkfma(A0, p, wp);
      p[0] = __uint_as_float(va.x & 0xffff0000u);  p[1] = __uint_as_float(vb2.x & 0xffff0000u);
      pkfma(A1, p, wp);
      p[0] = __uint_as_float(va.y << 16);          p[1] = __uint_as_float(vb2.y << 16);
      pkfma(A2, p, wp);
      p[0] = __uint_as_float(va.y & 0xffff0000u);  p[1] = __uint_as_float(vb2.y & 0xffff0000u);
      pkfma(A3, p, wp);
    }
  }
  float accx = A0[0] + A0[1];
  float accy = A1[0] + A1[1];
  float accz = A2[0] + A2[1];
  float accw = A3[0] + A3[1];
  for (int j = 64; j < deg; ++j) {       // overflow: recompute weight from record
    int src = sarr[start + j];
    unsigned int t2 = recs[(size_t)(start + j) * 8 + hc];
    float a = h2f((unsigned short)(t2 & 0xffffu)) + adst_c;
    a = fmaxf(a, NEG_SLOPE * a);
    float wj = __expf(a);
    uint2 v = ((const uint2*)(xhb + (((size_t)src) << 8)))[lane];
    accx = fmaf(__uint_as_float(v.x << 16), wj, accx);
    accy = fmaf(__uint_as_float(v.x & 0xffff0000u), wj, accy);
    accz = fmaf(__uint_as_float(v.y << 16), wj, accz);
    accw = fmaf(__uint_as_float(v.y & 0xffff0000u), wj, accw);
  }
  accx *= inv_c; accy *= inv_c; accz *= inv_c; accw *= inv_c;

  // head mean across hc (xor 8,16,32)
#pragma unroll
  for (int m = 8; m <= 32; m <<= 1) {
    accx += __shfl_xor(accx, m, 64);
    accy += __shfl_xor(accy, m, 64);
    accz += __shfl_xor(accz, m, 64);
    accw += __shfl_xor(accw, m, 64);
  }
  if (lane < 8) {
    float4 b = ((const float4*)bias)[lane];
    float4 o;
    o.x = accx * 0.125f + b.x;
    o.y = accy * 0.125f + b.y;
    o.z = accz * 0.125f + b.z;
    o.w = accw * 0.125f + b.w;
    ((float4*)&out[(size_t)n * C])[lane] = o;
  }
}

extern "C" void kernel_launch(void* const* d_in, const int* in_sizes, int n_in,
                              void* d_out, int out_size, void* d_ws, size_t ws_size,
                              hipStream_t stream) {
  const float* x        = (const float*)d_in[0];
  const int*   ei       = (const int*)d_in[1];
  const float* ea       = (const float*)d_in[2];
  const float* W        = (const float*)d_in[3];
  const float* W_edge   = (const float*)d_in[4];
  const float* att_src  = (const float*)d_in[5];
  const float* att_dst  = (const float*)d_in[6];
  const float* att_edge = (const float*)d_in[7];
  const float* bias     = (const float*)d_in[8];
  float* out = (float*)d_out;

  int N = in_sizes[0] / FIN;
  int E = in_sizes[1] / 2;
  int nb = (N + 255) / 256;
  int nde = (E + 255) / 256;
  int nx = (N + 127) / 128;

  char* ws = (char*)d_ws;
  auto take = [&](size_t bytes) {
    char* p = ws;
    ws += (bytes + 255) & ~(size_t)255;
    return p;
  };
  unsigned short* xhb    = (unsigned short*)take((size_t)N * HC * 2);
  float*          a_dst  = (float*)take((size_t)N * H * 4);
  unsigned short* a_srch = (unsigned short*)take((size_t)N * H * 2);
  unsigned int*   recs   = (unsigned int*)take((size_t)E * 32);
  int*            sarr   = (int*)take((size_t)E * 4);
  int*            deg    = (int*)take((size_t)N * 4);
  int*            rowptr = (int*)take((size_t)(N + 1) * 4);
  int*            rank   = (int*)take((size_t)E * 4);
  int*            bsum   = (int*)take((size_t)nb * 4);

  hipMemsetAsync(deg, 0, (size_t)N * 4, stream);
  k_fused<<<nde + 2 * nx, 256, 0, stream>>>(x, W, att_src, att_dst, ei, deg, rank,
                                            xhb, a_dst, a_srch, N, E, nde, nx);
  k_scan1<<<nb, 256, 0, stream>>>(deg, bsum, N);
  k_scan23<<<nb, 256, 0, stream>>>(deg, bsum, rowptr, N, E, nb);
  k_edge_scatter<<<(E + 511) / 512, 256, 0, stream>>>(ei, ea, W_edge, att_edge, a_srch, rowptr, rank, recs, sarr, E);
  k_node<<<(N + 3) / 4, 256, 0, stream>>>(xhb, a_srch, a_dst, recs, sarr, rowptr, bias, out, N);
}

// Round 7
// 281.265 us; speedup vs baseline: 2.1031x; 1.0651x over previous
//
#include <hip/hip_runtime.h>
#include <hip/hip_fp16.h>
#include <math.h>

#define H 8
#define C 32
#define HC 256      // H*C
#define FE 16
#define FIN 128
#define NEG_SLOPE 0.2f

typedef __attribute__((ext_vector_type(8))) short bf16x8;
typedef __attribute__((ext_vector_type(4))) float f32x4;
typedef __attribute__((ext_vector_type(2))) float f32x2;

__device__ __forceinline__ unsigned short f2bf(float f) {
  unsigned int u = __float_as_uint(f);
  unsigned int lsb = (u >> 16) & 1u;
  u += 0x7fffu + lsb;               // round-to-nearest-even
  return (unsigned short)(u >> 16);
}
__device__ __forceinline__ float bf2f(unsigned short s) {
  return __uint_as_float(((unsigned int)s) << 16);
}
__device__ __forceinline__ unsigned short f2h(float f) {
  return __half_as_ushort(__float2half(f));
}
__device__ __forceinline__ float h2f(unsigned short s) {
  return __half2float(__ushort_as_half(s));
}
// packed 2xf32 FMA: acc = x*w + acc (bit-exact == 2 scalar fmaf)
__device__ __forceinline__ void pkfma(f32x2& acc, f32x2 x, f32x2 w) {
  asm volatile("v_pk_fma_f32 %0, %1, %2, %0" : "+v"(acc) : "v"(x), "v"(w));
}

// split 8 fp32 into hi (truncated bf16) + lo (RNE bf16 of residual)
__device__ __forceinline__ void split8(const float* v, bf16x8& hi, bf16x8& lo) {
#pragma unroll
  for (int i = 0; i < 8; ++i) {
    unsigned int u = __float_as_uint(v[i]);
    unsigned int hu = u & 0xffff0000u;
    float r = v[i] - __uint_as_float(hu);
    hi[i] = (short)(hu >> 16);
    lo[i] = (short)f2bf(r);
  }
}

// ---------------- FUSED: xh GEMM (first 2*nx blocks) + edge-degree histogram (rest) ----------------
// GEMM blocks dispatch FIRST and occupy all CUs; latency-bound histogram blocks backfill
// free wave slots behind them -> true overlap (round-6 had the order reversed = serial phases).
__global__ __launch_bounds__(256) void k_fused(const float* __restrict__ x,
                                               const float* __restrict__ W,
                                               const float* __restrict__ att_src,
                                               const float* __restrict__ att_dst,
                                               const int* __restrict__ ei,
                                               int* __restrict__ deg,
                                               int* __restrict__ rank,
                                               unsigned short* __restrict__ xhb,
                                               float* __restrict__ a_dst,
                                               unsigned short* __restrict__ a_srch,
                                               int N, int E, int nde, int nx) {
  int t = threadIdx.x;
  if ((int)blockIdx.x >= 2 * nx) {
    // ---------- degree histogram path (backfills behind GEMM) ----------
    int e = (blockIdx.x - 2 * nx) * 256 + t;
    if (e < E) rank[e] = atomicAdd(&deg[ei[E + e]], 1);
    return;
  }
  // ---------- xh GEMM path ----------
  int bb = blockIdx.x;
  int by = (bb >= nx) ? 1 : 0;
  int bx = bb - by * nx;

  int w = t >> 6, lane = t & 63;
  int n15 = lane & 15, q = lane >> 4;
  int nodeBase = bx * 128 + w * 32;      // + nt*16 + n15
  int chBase = by * 128;                 // + mt*16 + (row idx)

  f32x4 acc[8][2];
#pragma unroll
  for (int mt = 0; mt < 8; ++mt)
#pragma unroll
    for (int nt = 0; nt < 2; ++nt) acc[mt][nt] = (f32x4)(0.f);

  for (int ks = 0; ks < 4; ++ks) {
    int kOff = ks * 32 + q * 8;
    bf16x8 Bhi[2], Blo[2];
#pragma unroll
    for (int nt = 0; nt < 2; ++nt) {
      int node = nodeBase + nt * 16 + n15;
      int rn = (node < N) ? node : (N - 1);
      const float* px = &x[(size_t)rn * FIN + kOff];
      float vb[8];
      *(float4*)&vb[0] = *(const float4*)px;
      *(float4*)&vb[4] = *(const float4*)(px + 4);
      split8(vb, Bhi[nt], Blo[nt]);
    }
#pragma unroll
    for (int mt = 0; mt < 8; ++mt) {
      int widx = ((chBase + mt * 16 + n15) << 7) + kOff;
      const float* pw = &W[widx];
      float wv8[8];
      *(float4*)&wv8[0] = *(const float4*)pw;
      *(float4*)&wv8[4] = *(const float4*)(pw + 4);
      bf16x8 Ahi, Alo;
      split8(wv8, Ahi, Alo);
#pragma unroll
      for (int nt = 0; nt < 2; ++nt) {
        acc[mt][nt] = __builtin_amdgcn_mfma_f32_16x16x32_bf16(Ahi, Bhi[nt], acc[mt][nt], 0, 0, 0);
        acc[mt][nt] = __builtin_amdgcn_mfma_f32_16x16x32_bf16(Ahi, Blo[nt], acc[mt][nt], 0, 0, 0);
        acc[mt][nt] = __builtin_amdgcn_mfma_f32_16x16x32_bf16(Alo, Bhi[nt], acc[mt][nt], 0, 0, 0);
      }
    }
  }

  // Epilogue. C/D layout: col(lane&15)=node, row=q*4+reg = channel within tile.
  float ps[2][4] = {{0.f,0.f,0.f,0.f},{0.f,0.f,0.f,0.f}};
  float pd[2][4] = {{0.f,0.f,0.f,0.f},{0.f,0.f,0.f,0.f}};
#pragma unroll
  for (int mt = 0; mt < 8; ++mt) {
    int hl = mt >> 1;
#pragma unroll
    for (int r = 0; r < 4; ++r) {
      int ch = chBase + mt * 16 + q * 4 + r;
      float as_c = att_src[ch], ad_c = att_dst[ch];
#pragma unroll
      for (int nt = 0; nt < 2; ++nt) {
        float val = acc[mt][nt][r];
        ps[nt][hl] = fmaf(val, as_c, ps[nt][hl]);
        pd[nt][hl] = fmaf(val, ad_c, pd[nt][hl]);
      }
    }
#pragma unroll
    for (int nt = 0; nt < 2; ++nt) {
      int node = nodeBase + nt * 16 + n15;
      if (node < N) {
        ushort4 us;
        us.x = f2bf(acc[mt][nt][0]); us.y = f2bf(acc[mt][nt][1]);
        us.z = f2bf(acc[mt][nt][2]); us.w = f2bf(acc[mt][nt][3]);
        *(ushort4*)&xhb[(size_t)node * HC + chBase + mt * 16 + q * 4] = us;
      }
    }
  }
#pragma unroll
  for (int nt = 0; nt < 2; ++nt)
#pragma unroll
    for (int hl = 0; hl < 4; ++hl) {
      ps[nt][hl] += __shfl_xor(ps[nt][hl], 16, 64);
      ps[nt][hl] += __shfl_xor(ps[nt][hl], 32, 64);
      pd[nt][hl] += __shfl_xor(pd[nt][hl], 16, 64);
      pd[nt][hl] += __shfl_xor(pd[nt][hl], 32, 64);
    }
  if (q == 0) {
#pragma unroll
    for (int nt = 0; nt < 2; ++nt) {
      int node = nodeBase + nt * 16 + n15;
      if (node < N) {
        *(float4*)&a_dst[node * H + by * 4] = make_float4(pd[nt][0], pd[nt][1], pd[nt][2], pd[nt][3]);
        unsigned int p0 = (unsigned int)f2h(ps[nt][0]) | ((unsigned int)f2h(ps[nt][1]) << 16);
        unsigned int p1 = (unsigned int)f2h(ps[nt][2]) | ((unsigned int)f2h(ps[nt][3]) << 16);
        *(uint2*)&a_srch[(size_t)node * H + by * 4] = make_uint2(p0, p1);
      }
    }
  }
}

// ---------------- scan stage 1: per-block sums ----------------
__global__ __launch_bounds__(256) void k_scan1(const int* __restrict__ deg,
                                               int* __restrict__ bsum, int N) {
  int t = threadIdx.x;
  int i = blockIdx.x * 256 + t;
  int v = (i < N) ? deg[i] : 0;
#pragma unroll
  for (int m = 1; m < 64; m <<= 1) v += __shfl_xor(v, m, 64);
  __shared__ int wsum[4];
  if ((t & 63) == 0) wsum[t >> 6] = v;
  __syncthreads();
  if (t == 0) bsum[blockIdx.x] = wsum[0] + wsum[1] + wsum[2] + wsum[3];
}

// ---------------- scan stage 2+3 fused: every block scans bsum in LDS, then local scan ----------------
__global__ __launch_bounds__(256) void k_scan23(const int* __restrict__ deg,
                                                const int* __restrict__ bsum,
                                                int* __restrict__ rowptr, int N, int E, int nb) {
  __shared__ int sb[256];
  __shared__ int buf[256];
  int t = threadIdx.x;
  sb[t] = (t < nb) ? bsum[t] : 0;
  int i = blockIdx.x * 256 + t;
  int v = (i < N) ? deg[i] : 0;
  buf[t] = v;
  __syncthreads();
  for (int off = 1; off < 256; off <<= 1) {
    int y1 = (t >= off) ? sb[t - off] : 0;
    int y2 = (t >= off) ? buf[t - off] : 0;
    __syncthreads();
    sb[t] += y1;
    buf[t] += y2;
    __syncthreads();
  }
  int bofs = (blockIdx.x == 0) ? 0 : sb[blockIdx.x - 1];
  if (i < N) rowptr[i] = bofs + buf[t] - v;
  if (i == 0) rowptr[N] = E;
}

// ---------------- per-edge (2 edges/thread): a_edge = ea @ M; fold fp16 a_src[src] into record ----------------
// record[pos] = 8 x uint32: lo16 = fp16(a_edge + a_src[src][h]), hi16 = fp16(a_edge)
__global__ __launch_bounds__(256) void k_edge_scatter(const int* __restrict__ ei,
                                                      const float* __restrict__ ea,
                                                      const float* __restrict__ W_edge,
                                                      const float* __restrict__ att_edge,
                                                      const unsigned short* __restrict__ a_srch,
                                                      const int* __restrict__ rowptr,
                                                      const int* __restrict__ rank,
                                                      unsigned int* __restrict__ recs,
                                                      int* __restrict__ sarr, int E) {
  __shared__ float Ms[FE * H];
  int t = threadIdx.x;
  if (t < FE * H) {          // M[f][h] = sum_c W_edge[(h*C+c)*FE+f] * att_edge[h*C+c]
    int f = t >> 3, h = t & 7;
    float acc = 0.f;
#pragma unroll
    for (int c = 0; c < C; ++c)
      acc += W_edge[(h * C + c) * FE + f] * att_edge[h * C + c];
    Ms[f * H + h] = acc;
  }
  __syncthreads();
  int e0 = blockIdx.x * 512 + t;
  int e1 = e0 + 256;
  bool va = (e0 < E), vb = (e1 < E);
  int ca = va ? e0 : 0, cb = vb ? e1 : 0;
  // ---- independent loads first (2 chains in flight) ----
  int s0 = ei[ca], d0 = ei[E + ca];
  int s1 = ei[cb], d1 = ei[E + cb];
  const float4* pA = (const float4*)&ea[(size_t)ca * FE];
  const float4* pB = (const float4*)&ea[(size_t)cb * FE];
  float4 A0 = pA[0], A1 = pA[1], A2 = pA[2], A3 = pA[3];
  float4 B0 = pB[0], B1 = pB[1], B2 = pB[2], B3 = pB[3];
  int rk0 = rank[ca], rk1 = rank[cb];
  // ---- one dependent hop, both chains issued together ----
  int rp0 = rowptr[d0], rp1 = rowptr[d1];
  uint4 asA = *(const uint4*)&a_srch[(size_t)s0 * H];
  uint4 asB = *(const uint4*)&a_srch[(size_t)s1 * H];

  float eavA[FE] = {A0.x, A0.y, A0.z, A0.w, A1.x, A1.y, A1.z, A1.w,
                    A2.x, A2.y, A2.z, A2.w, A3.x, A3.y, A3.z, A3.w};
  float eavB[FE] = {B0.x, B0.y, B0.z, B0.w, B1.x, B1.y, B1.z, B1.w,
                    B2.x, B2.y, B2.z, B2.w, B3.x, B3.y, B3.z, B3.w};
  float oA[H], oB[H];
#pragma unroll
  for (int h = 0; h < H; ++h) {
    float aa = 0.f, ab = 0.f;
#pragma unroll
    for (int f = 0; f < FE; ++f) {
      float m = Ms[f * H + h];
      aa += eavA[f] * m;
      ab += eavB[f] * m;
    }
    oA[h] = aa; oB[h] = ab;
  }
  unsigned int asw[2][4] = {{asA.x, asA.y, asA.z, asA.w}, {asB.x, asB.y, asB.z, asB.w}};
  if (va) {
    int pos = rp0 + rk0;
    unsigned int rec[H];
#pragma unroll
    for (int h = 0; h < H; ++h) {
      float asv = h2f((unsigned short)((h & 1) ? (asw[0][h >> 1] >> 16) : (asw[0][h >> 1] & 0xffffu)));
      rec[h] = (unsigned int)f2h(oA[h] + asv) | ((unsigned int)f2h(oA[h]) << 16);
    }
    uint4* rp = (uint4*)&recs[(size_t)pos * 8];
    rp[0] = make_uint4(rec[0], rec[1], rec[2], rec[3]);
    rp[1] = make_uint4(rec[4], rec[5], rec[6], rec[7]);
    sarr[pos] = s0;
  }
  if (vb) {
    int pos = rp1 + rk1;
    unsigned int rec[H];
#pragma unroll
    for (int h = 0; h < H; ++h) {
      float asv = h2f((unsigned short)((h & 1) ? (asw[1][h >> 1] >> 16) : (asw[1][h >> 1] & 0xffffu)));
      rec[h] = (unsigned int)f2h(oB[h] + asv) | ((unsigned int)f2h(oB[h]) << 16);
    }
    uint4* rp = (uint4*)&recs[(size_t)pos * 8];
    rp[0] = make_uint4(rec[0], rec[1], rec[2], rec[3]);
    rp[1] = make_uint4(rec[4], rec[5], rec[6], rec[7]);
    sarr[pos] = s1;
  }
}

// ---------------- wave-per-node: max-free single-pass softmax + pk_fma paired gather ----------------
// exp(alpha)/sum(exp(alpha)) == reference's max-shifted softmax; |alpha| <~ 12 so fp32 exp is safe.
// wlds layout pair-interleaved: idx = (j>>1)*16 + h*2 + (j&1), so a ds_read_b64 yields {w_j, w_j+1}.
__global__ __launch_bounds__(256) void k_node(const unsigned short* __restrict__ xhb,
                                              const unsigned short* __restrict__ a_srch,
                                              const float* __restrict__ a_dst,
                                              const unsigned int* __restrict__ recs,
                                              const int* __restrict__ sarr,
                                              const int* __restrict__ rowptr,
                                              const float* __restrict__ bias,
                                              float* __restrict__ out, int N) {
  __shared__ float wlds[4][512];   // pair-interleaved, j<64
  __shared__ int   slds[4][64];
  int wv = threadIdx.x >> 6;
  int lane = threadIdx.x & 63;
  int n = blockIdx.x * 4 + wv;
  if (n >= N) return;
  int start = rowptr[n];
  int deg = rowptr[n + 1] - start;
  int jmax = (deg < 64) ? deg : 64;
  int nit = (jmax + 7) >> 3;           // live 8-edge chunks (wave-uniform -> scalar branch)
  int padded = nit << 3;
  int h = lane & 7, esub = lane >> 3;
  float adst = a_dst[n * H + h];
  float asrc = h2f(a_srch[(size_t)n * H + h]);

  // src list -> LDS in ONE coalesced load; pad rows point at self (weight 0 in wlds)
  if (lane < padded) slds[wv][lane] = (lane < jmax) ? sarr[start + lane] : n;

  // ---- phase 1a: batch all record loads (no uses in between) ----
  const unsigned int* rb = recs + (size_t)start * 8 + lane;
  unsigned int u[8] = {0, 0, 0, 0, 0, 0, 0, 0};
#pragma unroll
  for (int it = 0; it < 8; ++it)
    if (it < nit) {
      int j = it * 8 + esub;
      if (j < jmax) u[it] = rb[it * 64];
    }

  // ---- phase 1b: w = exp(alpha) directly (no max pass); raw-ae sum for self loop ----
  int widx = ((esub >> 1) << 4) + (h << 1) + (esub & 1);   // pair-interleaved slot for edge j=it*8+esub
  float den = 0.f, psum = 0.f;
#pragma unroll
  for (int it = 0; it < 8; ++it)
    if (it < nit) {
      int j = it * 8 + esub;
      bool val = (j < jmax);
      float raw = h2f((unsigned short)(u[it] >> 16));                 // raw a_edge (0 when padded)
      float a = h2f((unsigned short)(u[it] & 0xffffu)) + adst;        // a_edge + a_src + a_dst
      a = fmaxf(a, NEG_SLOPE * a);                                    // leaky relu (slope<1)
      float w = val ? __expf(a) : 0.f;
      psum += val ? raw : 0.f;
      den += w;
      wlds[wv][it * 64 + widx] = w;     // zero-pad falls out naturally
    }
  for (int j0 = 64; j0 < deg; j0 += 8) {   // overflow deg>64 (rare)
    int j = j0 + esub;
    if (j < deg) {
      unsigned int t2 = recs[(size_t)(start + j) * 8 + h];
      psum += h2f((unsigned short)(t2 >> 16));
      float a = h2f((unsigned short)(t2 & 0xffffu)) + adst;
      a = fmaxf(a, NEG_SLOPE * a);
      den += __expf(a);
    }
  }
#pragma unroll
  for (int m = 8; m <= 32; m <<= 1) {
    den += __shfl_xor(den, m, 64);
    psum += __shfl_xor(psum, m, 64);
  }
  float aself = asrc + adst + psum / fmaxf((float)deg, 1.f);
  aself = fmaxf(aself, NEG_SLOPE * aself);
  float wself = __expf(aself);
  float inv = 1.f / (den + wself);

  // ---- phase 2: guard-free gather, edge-paired v_pk_fma_f32 accumulation ----
  int hc = lane >> 3;
  float inv_c  = __shfl(inv, hc, 64);
  float ws_c   = __shfl(wself, hc, 64);
  float adst_c = __shfl(adst, hc, 64);
  f32x2 A0, A1, A2, A3;
  {
    uint2 su = ((const uint2*)(xhb + (((size_t)n) << 8)))[lane];
    A0[0] = ws_c * __uint_as_float(su.x << 16);         A0[1] = 0.f;
    A1[0] = ws_c * __uint_as_float(su.x & 0xffff0000u); A1[1] = 0.f;
    A2[0] = ws_c * __uint_as_float(su.y << 16);         A2[1] = 0.f;
    A3[0] = ws_c * __uint_as_float(su.y & 0xffff0000u); A3[1] = 0.f;
  }
  for (int j0 = 0; j0 < padded; j0 += 8) {
    uint2 v[8];
#pragma unroll
    for (int k = 0; k < 8; ++k)
      v[k] = ((const uint2*)(xhb + (((size_t)slds[wv][j0 + k]) << 8)))[lane];
    // weight pairs {w_j, w_j+1}: one 8B LDS read each (idx = j0*8 + k2*16 + hc*2, 8B-aligned)
#pragma unroll
    for (int k2 = 0; k2 < 4; ++k2) {
      f32x2 wp = *(const f32x2*)&wlds[wv][j0 * 8 + k2 * 16 + hc * 2];
      uint2 va = v[2 * k2], vb2 = v[2 * k2 + 1];
      f32x2 p;
      p[0] = __uint_as_float(va.x << 16);          p[1] = __uint_as_float(vb2.x << 16);
      pkfma(A0, p, wp);
      p[0] = __uint_as_float(va.x & 0xffff0000u);  p[1] = __uint_as_float(vb2.x & 0xffff0000u);
      pkfma(A1, p, wp);
      p[0] = __uint_as_float(va.y << 16);          p[1] = __uint_as_float(vb2.y << 16);
      pkfma(A2, p, wp);
      p[0] = __uint_as_float(va.y & 0xffff0000u);  p[1] = __uint_as_float(vb2.y & 0xffff0000u);
      pkfma(A3, p, wp);
    }
  }
  float accx = A0[0] + A0[1];
  float accy = A1[0] + A1[1];
  float accz = A2[0] + A2[1];
  float accw = A3[0] + A3[1];
  for (int j = 64; j < deg; ++j) {       // overflow: recompute weight from record
    int src = sarr[start + j];
    unsigned int t2 = recs[(size_t)(start + j) * 8 + hc];
    float a = h2f((unsigned short)(t2 & 0xffffu)) + adst_c;
    a = fmaxf(a, NEG_SLOPE * a);
    float wj = __expf(a);
    uint2 v = ((const uint2*)(xhb + (((size_t)src) << 8)))[lane];
    accx = fmaf(__uint_as_float(v.x << 16), wj, accx);
    accy = fmaf(__uint_as_float(v.x & 0xffff0000u), wj, accy);
    accz = fmaf(__uint_as_float(v.y << 16), wj, accz);
    accw = fmaf(__uint_as_float(v.y & 0xffff0000u), wj, accw);
  }
  accx *= inv_c; accy *= inv_c; accz *= inv_c; accw *= inv_c;

  // head mean across hc (xor 8,16,32)
#pragma unroll
  for (int m = 8; m <= 32; m <<= 1) {
    accx += __shfl_xor(accx, m, 64);
    accy += __shfl_xor(accy, m, 64);
    accz += __shfl_xor(accz, m, 64);
    accw += __shfl_xor(accw, m, 64);
  }
  if (lane < 8) {
    float4 b = ((const float4*)bias)[lane];
    float4 o;
    o.x = accx * 0.125f + b.x;
    o.y = accy * 0.125f + b.y;
    o.z = accz * 0.125f + b.z;
    o.w = accw * 0.125f + b.w;
    ((float4*)&out[(size_t)n * C])[lane] = o;
  }
}

extern "C" void kernel_launch(void* const* d_in, const int* in_sizes, int n_in,
                              void* d_out, int out_size, void* d_ws, size_t ws_size,
                              hipStream_t stream) {
  const float* x        = (const float*)d_in[0];
  const int*   ei       = (const int*)d_in[1];
  const float* ea       = (const float*)d_in[2];
  const float* W        = (const float*)d_in[3];
  const float* W_edge   = (const float*)d_in[4];
  const float* att_src  = (const float*)d_in[5];
  const float* att_dst  = (const float*)d_in[6];
  const float* att_edge = (const float*)d_in[7];
  const float* bias     = (const float*)d_in[8];
  float* out = (float*)d_out;

  int N = in_sizes[0] / FIN;
  int E = in_sizes[1] / 2;
  int nb = (N + 255) / 256;
  int nde = (E + 255) / 256;
  int nx = (N + 127) / 128;

  char* ws = (char*)d_ws;
  auto take = [&](size_t bytes) {
    char* p = ws;
    ws += (bytes + 255) & ~(size_t)255;
    return p;
  };
  unsigned short* xhb    = (unsigned short*)take((size_t)N * HC * 2);
  float*          a_dst  = (float*)take((size_t)N * H * 4);
  unsigned short* a_srch = (unsigned short*)take((size_t)N * H * 2);
  unsigned int*   recs   = (unsigned int*)take((size_t)E * 32);
  int*            sarr   = (int*)take((size_t)E * 4);
  int*            deg    = (int*)take((size_t)N * 4);
  int*            rowptr = (int*)take((size_t)(N + 1) * 4);
  int*            rank   = (int*)take((size_t)E * 4);
  int*            bsum   = (int*)take((size_t)nb * 4);

  hipMemsetAsync(deg, 0, (size_t)N * 4, stream);
  k_fused<<<nde + 2 * nx, 256, 0, stream>>>(x, W, att_src, att_dst, ei, deg, rank,
                                            xhb, a_dst, a_srch, N, E, nde, nx);
  k_scan1<<<nb, 256, 0, stream>>>(deg, bsum, N);
  k_scan23<<<nb, 256, 0, stream>>>(deg, bsum, rowptr, N, E, nb);
  k_edge_scatter<<<(E + 511) / 512, 256, 0, stream>>>(ei, ea, W_edge, att_edge, a_srch, rowptr, rank, recs, sarr, E);
  k_node<<<(N + 3) / 4, 256, 0, stream>>>(xhb, a_srch, a_dst, recs, sarr, rowptr, bias, out, N);
}